// Round 1
// baseline (1098.463 us; speedup 1.0000x reference)
//
#include <hip/hip_runtime.h>
#include <stdint.h>

#define NEG_SLOPE 0.2f

static inline int ceil_div(int a, int b){ return (a + b - 1) / b; }

// ---------------------------------------------------------------- CSR build
__global__ __launch_bounds__(256) void zero_i32(int* __restrict__ p, int n){
  int i = blockIdx.x * 256 + threadIdx.x;
  if (i < n) p[i] = 0;
}

__global__ __launch_bounds__(256) void hist_kernel(const int* __restrict__ dst,
                                                   int* __restrict__ counts, int E){
  int i = blockIdx.x * 256 + threadIdx.x;
  if (i < E) atomicAdd(counts + dst[i], 1);
}

// single-block exclusive scan of counts[n] -> offsets[n+1], cursor[n]
__global__ __launch_bounds__(1024) void scan_kernel(const int* __restrict__ counts,
                                                    int* __restrict__ offsets,
                                                    int* __restrict__ cursor, int n){
  __shared__ int lds[1024];
  const int tid = threadIdx.x;
  const int chunk = (n + 1023) >> 10;
  const int beg = tid * chunk;
  const int end = min(beg + chunk, n);
  int s = 0;
  for (int i = beg; i < end; ++i) s += counts[i];
  lds[tid] = s;
  __syncthreads();
  // Hillis-Steele inclusive scan over the 1024 per-thread sums
  for (int off = 1; off < 1024; off <<= 1){
    int t = 0;
    if (tid >= off) t = lds[tid - off];
    __syncthreads();
    if (tid >= off) lds[tid] += t;
    __syncthreads();
  }
  int run = lds[tid] - s;              // exclusive prefix for this thread's chunk
  for (int i = beg; i < end; ++i){
    offsets[i] = run;
    cursor[i]  = run;
    run += counts[i];
  }
  if (tid == 1023) offsets[n] = lds[1023];
}

__global__ __launch_bounds__(256) void scatter_kernel(const int* __restrict__ srcv,
                                                      const int* __restrict__ dstv,
                                                      int* __restrict__ cursor,
                                                      int* __restrict__ sorted_src, int E){
  int i = blockIdx.x * 256 + threadIdx.x;
  if (i < E){
    int d = dstv[i];
    int pos = atomicAdd(cursor + d, 1);
    sorted_src[pos] = srcv[i];
  }
}

// ------------------------------------------------- per-layer: h = x@W (+ fused a·h)
// block = 256 threads (4 waves), 32 rows per block. W (16 KB) + x-tile (8 KB) in LDS.
__global__ __launch_bounds__(256) void gemm_fused(const float* __restrict__ x,
                                                  const float* __restrict__ W,
                                                  const float* __restrict__ a_src,
                                                  const float* __restrict__ a_dst,
                                                  float* __restrict__ h,
                                                  float* __restrict__ s_src,
                                                  float* __restrict__ s_dst, int N){
  __shared__ float wlds[64 * 64];
  __shared__ float xlds[32 * 64];
  const int tid = threadIdx.x;
  const int row0 = blockIdx.x * 32;
  for (int i = tid; i < 64 * 64; i += 256) wlds[i] = W[i];
  for (int i = tid; i < 32 * 64; i += 256){
    int r = row0 + (i >> 6);
    xlds[i] = (r < N) ? x[r * 64 + (i & 63)] : 0.0f;
  }
  __syncthreads();
  const int wave = tid >> 6;
  const int lane = tid & 63;
  const float asv = a_src[lane];
  const float adv = a_dst[lane];
  for (int r = wave; r < 32; r += 4){
    int row = row0 + r;
    if (row >= N) break;               // rows increase per wave -> uniform exit
    float acc = 0.0f;
    #pragma unroll
    for (int k = 0; k < 64; ++k)
      acc = fmaf(xlds[r * 64 + k], wlds[k * 64 + lane], acc);
    h[row * 64 + lane] = acc;
    // fused per-head dot products: s_src[row][h] = sum_c h[row,h,c]*a_src[h,c]
    float ps = acc * asv;
    float pd = acc * adv;
    #pragma unroll
    for (int off = 1; off < 8; off <<= 1){
      ps += __shfl_xor(ps, off, 64);
      pd += __shfl_xor(pd, off, 64);
    }
    if ((lane & 7) == 0){
      s_src[row * 8 + (lane >> 3)] = ps;
      s_dst[row * 8 + (lane >> 3)] = pd;
    }
  }
}

// ------------------------------------- per-layer: segment softmax + aggregation
// one wave per node; lane = h*8+c (so h[src*64+lane] is a coalesced 256B load,
// softmax state is replicated within each 8-lane head group -> no cross-lane ops)
__global__ __launch_bounds__(256) void aggregate(const float* __restrict__ h,
                                                 const float* __restrict__ s_src,
                                                 const float* __restrict__ s_dst,
                                                 const int* __restrict__ offsets,
                                                 const int* __restrict__ sorted_src,
                                                 const float* __restrict__ bias,
                                                 float* __restrict__ out, int N){
  const int gtid = blockIdx.x * 256 + threadIdx.x;
  const int node = gtid >> 6;
  const int lane = threadIdx.x & 63;
  if (node >= N) return;
  const int head = lane >> 3;
  const float sdst = s_dst[node * 8 + head];
  const int beg = offsets[node];
  const int end = offsets[node + 1];

  // self-loop score (PyG add_self_loops=True)
  float sc = s_src[node * 8 + head] + sdst;
  const float lr_self = (sc > 0.0f) ? sc : NEG_SLOPE * sc;

  // pass 1: per-head max over incoming edges
  float m = lr_self;
  for (int i = beg; i < end; ++i){
    int s = sorted_src[i];
    float v = s_src[s * 8 + head] + sdst;
    v = (v > 0.0f) ? v : NEG_SLOPE * v;
    m = fmaxf(m, v);
  }

  // pass 2: exp-sum + weighted aggregation
  float f = __expf(lr_self - m);
  float z = f;
  float acc = f * h[node * 64 + lane];
  for (int i = beg; i < end; ++i){
    int s = sorted_src[i];
    float v = s_src[s * 8 + head] + sdst;
    v = (v > 0.0f) ? v : NEG_SLOPE * v;
    float e = __expf(v - m);
    z += e;
    acc = fmaf(e, h[s * 64 + lane], acc);
  }
  out[node * 64 + lane] = acc / (z + 1e-16f) + bias[lane];
}

// ---------------------------------------------------------------- launch
extern "C" void kernel_launch(void* const* d_in, const int* in_sizes, int n_in,
                              void* d_out, int out_size, void* d_ws, size_t ws_size,
                              hipStream_t stream){
  const float* x0   = (const float*)d_in[0];
  const int*   eidx = (const int*)  d_in[1];   // [2, E] int32
  const float* Ws   = (const float*)d_in[2];   // [L, 64, 64]
  const float* asrc = (const float*)d_in[3];   // [L, 8, 8]
  const float* adst = (const float*)d_in[4];   // [L, 8, 8]
  const float* bias = (const float*)d_in[5];   // [L, 64]

  const int N = in_sizes[0] / 64;
  const int E = in_sizes[1] / 2;
  const int L = in_sizes[2] / (64 * 64);

  // carve workspace (256B-aligned chunks)
  char* ws = (char*)d_ws;
  size_t off = 0;
  auto alloc = [&](size_t bytes) -> void* {
    void* p = ws + off;
    off = (off + bytes + 255) & ~(size_t)255;
    return p;
  };
  float* hbuf    = (float*)alloc((size_t)N * 64 * sizeof(float));
  float* bufA    = (float*)alloc((size_t)N * 64 * sizeof(float));
  float* bufB    = (float*)alloc((size_t)N * 64 * sizeof(float));
  float* ssrc    = (float*)alloc((size_t)N * 8 * sizeof(float));
  float* sdstb   = (float*)alloc((size_t)N * 8 * sizeof(float));
  int*   counts  = (int*)alloc((size_t)N * sizeof(int));
  int*   offsets = (int*)alloc((size_t)(N + 1) * sizeof(int));
  int*   cursor  = (int*)alloc((size_t)N * sizeof(int));
  int*   ssorted = (int*)alloc((size_t)E * sizeof(int));

  const int* esrc = eidx;
  const int* edst = eidx + E;

  // CSR by destination — built once, reused by all 8 layers
  zero_i32<<<ceil_div(N, 256), 256, 0, stream>>>(counts, N);
  hist_kernel<<<ceil_div(E, 256), 256, 0, stream>>>(edst, counts, E);
  scan_kernel<<<1, 1024, 0, stream>>>(counts, offsets, cursor, N);
  scatter_kernel<<<ceil_div(E, 256), 256, 0, stream>>>(esrc, edst, cursor, ssorted, E);

  float* bufs[2] = {bufA, bufB};
  for (int l = 0; l < L; ++l){
    const float* xin  = (l == 0)     ? x0 : bufs[(l - 1) & 1];
    float*       xout = (l == L - 1) ? (float*)d_out : bufs[l & 1];
    gemm_fused<<<ceil_div(N, 32), 256, 0, stream>>>(
        xin, Ws + (size_t)l * 64 * 64, asrc + l * 64, adst + l * 64,
        hbuf, ssrc, sdstb, N);
    aggregate<<<ceil_div(N * 64, 256), 256, 0, stream>>>(
        hbuf, ssrc, sdstb, offsets, ssorted, bias + l * 64, xout, N);
  }
}

// Round 2
// 489.515 us; speedup vs baseline: 2.2440x; 2.2440x over previous
//
#include <hip/hip_runtime.h>
#include <stdint.h>

#define NEG_SLOPE 0.2f

static inline int ceil_div(int a, int b){ return (a + b - 1) / b; }

// ---------------------------------------------------------------- CSR build
__global__ __launch_bounds__(256) void zero_i32(int* __restrict__ p, int n){
  int i = blockIdx.x * 256 + threadIdx.x;
  if (i < n) p[i] = 0;
}

__global__ __launch_bounds__(256) void hist_kernel(const int* __restrict__ dst,
                                                   int* __restrict__ counts, int E){
  int i = blockIdx.x * 256 + threadIdx.x;
  if (i < E) atomicAdd(counts + dst[i], 1);
}

// single-block exclusive scan of counts[n] -> offsets[n+1], cursor[n]
__global__ __launch_bounds__(1024) void scan_kernel(const int* __restrict__ counts,
                                                    int* __restrict__ offsets,
                                                    int* __restrict__ cursor, int n){
  __shared__ int lds[1024];
  const int tid = threadIdx.x;
  const int chunk = (n + 1023) >> 10;
  const int beg = tid * chunk;
  const int end = min(beg + chunk, n);
  int s = 0;
  for (int i = beg; i < end; ++i) s += counts[i];
  lds[tid] = s;
  __syncthreads();
  for (int off = 1; off < 1024; off <<= 1){
    int t = 0;
    if (tid >= off) t = lds[tid - off];
    __syncthreads();
    if (tid >= off) lds[tid] += t;
    __syncthreads();
  }
  int run = lds[tid] - s;
  for (int i = beg; i < end; ++i){
    offsets[i] = run;
    cursor[i]  = run;
    run += counts[i];
  }
  if (tid == 1023) offsets[n] = lds[1023];
}

__global__ __launch_bounds__(256) void scatter_kernel(const int* __restrict__ srcv,
                                                      const int* __restrict__ dstv,
                                                      int* __restrict__ cursor,
                                                      int* __restrict__ sorted_src, int E){
  int i = blockIdx.x * 256 + threadIdx.x;
  if (i < E){
    int d = dstv[i];
    int pos = atomicAdd(cursor + d, 1);
    sorted_src[pos] = srcv[i];
  }
}

// ------------------------------------------------- per-layer: h = x@W (+ fused a·h)
// block = 256 (4 waves), 32 rows/block. W column in 64 VGPRs per wave (L2-hit
// coalesced load); x broadcast from LDS via float4 -> 16 ds_read_b128 + 64 FMA/row.
__global__ __launch_bounds__(256) void gemm_fused(const float* __restrict__ x,
                                                  const float* __restrict__ W,
                                                  const float* __restrict__ a_src,
                                                  const float* __restrict__ a_dst,
                                                  float* __restrict__ h,
                                                  float* __restrict__ s_src,
                                                  float* __restrict__ s_dst, int N){
  __shared__ float xlds[32 * 64];
  const int tid  = threadIdx.x;
  const int lane = tid & 63;
  const int wave = tid >> 6;
  const int row0 = blockIdx.x * 32;

  // W column `lane` into registers (16 KB re-read per wave, L2-resident)
  float wreg[64];
  #pragma unroll
  for (int k = 0; k < 64; ++k) wreg[k] = W[k * 64 + lane];

  // stage x tile as float4 (512 float4s, 2 per thread)
  {
    const float4* xg = (const float4*)x;
    float4* xl = (float4*)xlds;
    #pragma unroll
    for (int i = tid; i < 512; i += 256){
      int r = row0 + (i >> 4);
      float4 v = {0.f, 0.f, 0.f, 0.f};
      if (r < N) v = xg[(size_t)r * 16 + (i & 15)];
      xl[i] = v;
    }
  }
  __syncthreads();

  const float asv = a_src[lane];
  const float adv = a_dst[lane];

  for (int r = wave; r < 32; r += 4){
    int row = row0 + r;
    if (row >= N) break;               // uniform within wave
    const float4* xr = (const float4*)(xlds + r * 64);
    float acc = 0.0f;
    #pragma unroll
    for (int kk = 0; kk < 16; ++kk){
      float4 xv = xr[kk];              // LDS broadcast (same addr all lanes)
      acc = fmaf(xv.x, wreg[4*kk+0], acc);
      acc = fmaf(xv.y, wreg[4*kk+1], acc);
      acc = fmaf(xv.z, wreg[4*kk+2], acc);
      acc = fmaf(xv.w, wreg[4*kk+3], acc);
    }
    h[(size_t)row * 64 + lane] = acc;
    // fused per-head dot products
    float ps = acc * asv;
    float pd = acc * adv;
    #pragma unroll
    for (int off = 1; off < 8; off <<= 1){
      ps += __shfl_xor(ps, off, 64);
      pd += __shfl_xor(pd, off, 64);
    }
    if ((lane & 7) == 0){
      s_src[row * 8 + (lane >> 3)] = ps;
      s_dst[row * 8 + (lane >> 3)] = pd;
    }
  }
}

// ------------------------------------- per-layer: segment softmax + aggregation
// one wave per node; lane = e8*8 + c8: c8 = head (owns channels 8c8..8c8+7),
// e8 = edge slot (8 edges in flight). Virtual edge 0 = self-loop.
// All reductions via __shfl_xor(8,16,32) butterflies; zero LDS.
__global__ __launch_bounds__(256) void aggregate(const float* __restrict__ h,
                                                 const float* __restrict__ s_src,
                                                 const float* __restrict__ s_dst,
                                                 const int* __restrict__ offsets,
                                                 const int* __restrict__ sorted_src,
                                                 const float* __restrict__ bias,
                                                 float* __restrict__ out, int N){
  const int node = (blockIdx.x * 256 + threadIdx.x) >> 6;
  if (node >= N) return;
  const int lane = threadIdx.x & 63;
  const int c8 = lane & 7;            // head / channel group
  const int e8 = lane >> 3;           // edge slot
  const int beg = offsets[node];
  const int nv  = offsets[node + 1] - beg + 1;   // +1 for self-loop
  const float sdst = s_dst[node * 8 + c8];

  // pass 1: per-head max (lane-parallel over edges)
  float m = -3.0e38f;
  for (int v = e8; v < nv; v += 8){
    int s = (v == 0) ? node : sorted_src[beg + v - 1];
    float sc = s_src[s * 8 + c8] + sdst;
    sc = (sc > 0.0f) ? sc : NEG_SLOPE * sc;
    m = fmaxf(m, sc);
  }
  m = fmaxf(m, __shfl_xor(m, 8, 64));
  m = fmaxf(m, __shfl_xor(m, 16, 64));
  m = fmaxf(m, __shfl_xor(m, 32, 64));

  // pass 2: exp-sum + weighted aggregation (8 edges/iter across the wave)
  float z = 0.0f;
  float acc[8];
  #pragma unroll
  for (int j = 0; j < 8; ++j) acc[j] = 0.0f;

  for (int v = e8; v < nv; v += 8){
    int s = (v == 0) ? node : sorted_src[beg + v - 1];
    float sc = s_src[s * 8 + c8] + sdst;
    sc = (sc > 0.0f) ? sc : NEG_SLOPE * sc;
    float e = __expf(sc - m);
    z += e;
    const float4* hp = (const float4*)(h + (size_t)s * 64 + c8 * 8);
    float4 h0 = hp[0];
    float4 h1 = hp[1];
    acc[0] = fmaf(e, h0.x, acc[0]);
    acc[1] = fmaf(e, h0.y, acc[1]);
    acc[2] = fmaf(e, h0.z, acc[2]);
    acc[3] = fmaf(e, h0.w, acc[3]);
    acc[4] = fmaf(e, h1.x, acc[4]);
    acc[5] = fmaf(e, h1.y, acc[5]);
    acc[6] = fmaf(e, h1.z, acc[6]);
    acc[7] = fmaf(e, h1.w, acc[7]);
  }

  // butterfly reduce z + acc over the 8 e8-groups
  #pragma unroll
  for (int off = 8; off < 64; off <<= 1){
    z += __shfl_xor(z, off, 64);
    #pragma unroll
    for (int j = 0; j < 8; ++j) acc[j] += __shfl_xor(acc[j], off, 64);
  }

  if (e8 == 0){
    float inv = 1.0f / (z + 1e-16f);
    const float4* bp = (const float4*)(bias + c8 * 8);
    float4 b0 = bp[0], b1 = bp[1];
    float4 o0, o1;
    o0.x = acc[0] * inv + b0.x;
    o0.y = acc[1] * inv + b0.y;
    o0.z = acc[2] * inv + b0.z;
    o0.w = acc[3] * inv + b0.w;
    o1.x = acc[4] * inv + b1.x;
    o1.y = acc[5] * inv + b1.y;
    o1.z = acc[6] * inv + b1.z;
    o1.w = acc[7] * inv + b1.w;
    float4* op = (float4*)(out + (size_t)node * 64 + c8 * 8);
    op[0] = o0;
    op[1] = o1;
  }
}

// ---------------------------------------------------------------- launch
extern "C" void kernel_launch(void* const* d_in, const int* in_sizes, int n_in,
                              void* d_out, int out_size, void* d_ws, size_t ws_size,
                              hipStream_t stream){
  const float* x0   = (const float*)d_in[0];
  const int*   eidx = (const int*)  d_in[1];   // [2, E]
  const float* Ws   = (const float*)d_in[2];   // [L, 64, 64]
  const float* asrc = (const float*)d_in[3];   // [L, 8, 8]
  const float* adst = (const float*)d_in[4];   // [L, 8, 8]
  const float* bias = (const float*)d_in[5];   // [L, 64]

  const int N = in_sizes[0] / 64;
  const int E = in_sizes[1] / 2;
  const int L = in_sizes[2] / (64 * 64);

  char* ws = (char*)d_ws;
  size_t off = 0;
  auto alloc = [&](size_t bytes) -> void* {
    void* p = ws + off;
    off = (off + bytes + 255) & ~(size_t)255;
    return p;
  };
  float* hbuf    = (float*)alloc((size_t)N * 64 * sizeof(float));
  float* bufA    = (float*)alloc((size_t)N * 64 * sizeof(float));
  float* bufB    = (float*)alloc((size_t)N * 64 * sizeof(float));
  float* ssrc    = (float*)alloc((size_t)N * 8 * sizeof(float));
  float* sdstb   = (float*)alloc((size_t)N * 8 * sizeof(float));
  int*   counts  = (int*)alloc((size_t)N * sizeof(int));
  int*   offsets = (int*)alloc((size_t)(N + 1) * sizeof(int));
  int*   cursor  = (int*)alloc((size_t)N * sizeof(int));
  int*   ssorted = (int*)alloc((size_t)E * sizeof(int));

  const int* esrc = eidx;
  const int* edst = eidx + E;

  // CSR by destination — built once, reused by all layers
  zero_i32<<<ceil_div(N, 256), 256, 0, stream>>>(counts, N);
  hist_kernel<<<ceil_div(E, 256), 256, 0, stream>>>(edst, counts, E);
  scan_kernel<<<1, 1024, 0, stream>>>(counts, offsets, cursor, N);
  scatter_kernel<<<ceil_div(E, 256), 256, 0, stream>>>(esrc, edst, cursor, ssorted, E);

  float* bufs[2] = {bufA, bufB};
  for (int l = 0; l < L; ++l){
    const float* xin  = (l == 0)     ? x0 : bufs[(l - 1) & 1];
    float*       xout = (l == L - 1) ? (float*)d_out : bufs[l & 1];
    gemm_fused<<<ceil_div(N, 32), 256, 0, stream>>>(
        xin, Ws + (size_t)l * 64 * 64, asrc + l * 64, adst + l * 64,
        hbuf, ssrc, sdstb, N);
    aggregate<<<ceil_div(N * 64, 256), 256, 0, stream>>>(
        hbuf, ssrc, sdstb, offsets, ssorted, bias + l * 64, xout, N);
  }
}

// Round 4
// 440.041 us; speedup vs baseline: 2.4963x; 1.1124x over previous
//
#include <hip/hip_runtime.h>
#include <stdint.h>

#define NEG_SLOPE 0.2f

static inline int ceil_div(int a, int b){ return (a + b - 1) / b; }

// ---------------------------------------------------------------- CSR build
__global__ __launch_bounds__(256) void zero_i32(int* __restrict__ p, int n){
  int i = blockIdx.x * 256 + threadIdx.x;
  if (i < n) p[i] = 0;
}

__global__ __launch_bounds__(256) void hist_kernel(const int* __restrict__ dst,
                                                   int* __restrict__ counts, int E){
  int i = blockIdx.x * 256 + threadIdx.x;
  if (i < E) atomicAdd(counts + dst[i], 1);
}

// single-block exclusive scan of counts[n] -> offsets[n+1], cursor[n]
__global__ __launch_bounds__(1024) void scan_kernel(const int* __restrict__ counts,
                                                    int* __restrict__ offsets,
                                                    int* __restrict__ cursor, int n){
  __shared__ int lds[1024];
  const int tid = threadIdx.x;
  const int chunk = (n + 1023) >> 10;
  const int beg = tid * chunk;
  const int end = min(beg + chunk, n);
  int s = 0;
  for (int i = beg; i < end; ++i) s += counts[i];
  lds[tid] = s;
  __syncthreads();
  for (int off = 1; off < 1024; off <<= 1){
    int t = 0;
    if (tid >= off) t = lds[tid - off];
    __syncthreads();
    if (tid >= off) lds[tid] += t;
    __syncthreads();
  }
  int run = lds[tid] - s;
  for (int i = beg; i < end; ++i){
    offsets[i] = run;
    cursor[i]  = run;
    run += counts[i];
  }
  if (tid == 1023) offsets[n] = lds[1023];
}

__global__ __launch_bounds__(256) void scatter_kernel(const int* __restrict__ srcv,
                                                      const int* __restrict__ dstv,
                                                      int* __restrict__ cursor,
                                                      int* __restrict__ sorted_src, int E){
  int i = blockIdx.x * 256 + threadIdx.x;
  if (i < E){
    int d = dstv[i];
    int pos = atomicAdd(cursor + d, 1);
    sorted_src[pos] = srcv[i];
  }
}

// ------------------------------------------------- per-layer: h = x@W (+ fused a·h)
__global__ __launch_bounds__(256) void gemm_fused(const float* __restrict__ x,
                                                  const float* __restrict__ W,
                                                  const float* __restrict__ a_src,
                                                  const float* __restrict__ a_dst,
                                                  float* __restrict__ h,
                                                  float* __restrict__ s_src,
                                                  float* __restrict__ s_dst, int N){
  __shared__ float xlds[32 * 64];
  const int tid  = threadIdx.x;
  const int lane = tid & 63;
  const int wave = tid >> 6;
  const int row0 = blockIdx.x * 32;

  // W column `lane` into registers (L2-resident re-read)
  float wreg[64];
  #pragma unroll
  for (int k = 0; k < 64; ++k) wreg[k] = W[k * 64 + lane];

  {
    const float4* xg = (const float4*)x;
    float4* xl = (float4*)xlds;
    #pragma unroll
    for (int i = tid; i < 512; i += 256){
      int r = row0 + (i >> 4);
      float4 v = {0.f, 0.f, 0.f, 0.f};
      if (r < N) v = xg[(size_t)r * 16 + (i & 15)];
      xl[i] = v;
    }
  }
  __syncthreads();

  const float asv = a_src[lane];
  const float adv = a_dst[lane];

  for (int r = wave; r < 32; r += 4){
    int row = row0 + r;
    if (row >= N) break;               // uniform within wave
    const float4* xr = (const float4*)(xlds + r * 64);
    float acc = 0.0f;
    #pragma unroll
    for (int kk = 0; kk < 16; ++kk){
      float4 xv = xr[kk];              // LDS broadcast
      acc = fmaf(xv.x, wreg[4*kk+0], acc);
      acc = fmaf(xv.y, wreg[4*kk+1], acc);
      acc = fmaf(xv.z, wreg[4*kk+2], acc);
      acc = fmaf(xv.w, wreg[4*kk+3], acc);
    }
    h[(size_t)row * 64 + lane] = acc;
    float ps = acc * asv;
    float pd = acc * adv;
    #pragma unroll
    for (int off = 1; off < 8; off <<= 1){
      ps += __shfl_xor(ps, off, 64);
      pd += __shfl_xor(pd, off, 64);
    }
    if ((lane & 7) == 0){
      s_src[row * 8 + (lane >> 3)] = ps;
      s_dst[row * 8 + (lane >> 3)] = pd;
    }
  }
}

// ------------------------------------- per-layer: segment softmax + aggregation
// one wave per node; lane = e8*8 + c8 (c8 = head, e8 = edge slot).
// Fast path (nv<=64, covers ~all nodes): fully unrolled, 3 independent-load
// phases (indices -> scores -> h rows) so the memory system pipelines all
// gathers; only ~3 dependent round-trips per node instead of ~10.
__global__ __launch_bounds__(256) void aggregate(const float* __restrict__ h,
                                                 const float* __restrict__ s_src,
                                                 const float* __restrict__ s_dst,
                                                 const int* __restrict__ offsets,
                                                 const int* __restrict__ sorted_src,
                                                 const float* __restrict__ bias,
                                                 float* __restrict__ out, int N){
  const int node = (blockIdx.x * 256 + threadIdx.x) >> 6;
  if (node >= N) return;
  const int lane = threadIdx.x & 63;
  const int c8 = lane & 7;            // head / channel group
  const int e8 = lane >> 3;           // edge slot
  const int beg = offsets[node];
  const int nv  = offsets[node + 1] - beg + 1;   // +1 self-loop (slot 0)
  const float sdst = s_dst[node * 8 + c8];

  float m = -3.0e38f;
  float z = 0.0f;
  float acc[8];
  #pragma unroll
  for (int j = 0; j < 8; ++j) acc[j] = 0.0f;

  if (nv <= 64){
    const int cnt = (e8 < nv) ? ((nv - e8 + 7) >> 3) : 0;
    // phase 1: batch-load edge indices (independent loads)
    int sidx[8];
    #pragma unroll
    for (int j = 0; j < 8; ++j){
      int v = e8 + 8 * j;
      if (j < cnt) sidx[j] = (v == 0) ? node : sorted_src[beg + v - 1];
    }
    // phase 2: batch-gather scores (each dep only on its own sidx[j])
    float sc[8];
    #pragma unroll
    for (int j = 0; j < 8; ++j){
      if (j < cnt){
        float s = s_src[sidx[j] * 8 + c8] + sdst;
        sc[j] = (s > 0.0f) ? s : NEG_SLOPE * s;
        m = fmaxf(m, sc[j]);
      }
    }
    m = fmaxf(m, __shfl_xor(m, 8, 64));
    m = fmaxf(m, __shfl_xor(m, 16, 64));
    m = fmaxf(m, __shfl_xor(m, 32, 64));
    // phase 3: exp + batch h-gather (addresses already known)
    #pragma unroll
    for (int j = 0; j < 8; ++j){
      if (j < cnt){
        float e = __expf(sc[j] - m);
        z += e;
        const float4* hp = (const float4*)(h + (size_t)sidx[j] * 64 + c8 * 8);
        float4 h0 = hp[0];
        float4 h1 = hp[1];
        acc[0] = fmaf(e, h0.x, acc[0]);
        acc[1] = fmaf(e, h0.y, acc[1]);
        acc[2] = fmaf(e, h0.z, acc[2]);
        acc[3] = fmaf(e, h0.w, acc[3]);
        acc[4] = fmaf(e, h1.x, acc[4]);
        acc[5] = fmaf(e, h1.y, acc[5]);
        acc[6] = fmaf(e, h1.z, acc[6]);
        acc[7] = fmaf(e, h1.w, acc[7]);
      }
    }
  } else {
    // slow streaming path (rare: nv > 64)
    for (int v = e8; v < nv; v += 8){
      int s = (v == 0) ? node : sorted_src[beg + v - 1];
      float scv = s_src[s * 8 + c8] + sdst;
      scv = (scv > 0.0f) ? scv : NEG_SLOPE * scv;
      m = fmaxf(m, scv);
    }
    m = fmaxf(m, __shfl_xor(m, 8, 64));
    m = fmaxf(m, __shfl_xor(m, 16, 64));
    m = fmaxf(m, __shfl_xor(m, 32, 64));
    for (int v = e8; v < nv; v += 8){
      int s = (v == 0) ? node : sorted_src[beg + v - 1];
      float scv = s_src[s * 8 + c8] + sdst;
      scv = (scv > 0.0f) ? scv : NEG_SLOPE * scv;
      float e = __expf(scv - m);
      z += e;
      const float4* hp = (const float4*)(h + (size_t)s * 64 + c8 * 8);
      float4 h0 = hp[0];
      float4 h1 = hp[1];
      acc[0] = fmaf(e, h0.x, acc[0]);
      acc[1] = fmaf(e, h0.y, acc[1]);
      acc[2] = fmaf(e, h0.z, acc[2]);
      acc[3] = fmaf(e, h0.w, acc[3]);
      acc[4] = fmaf(e, h1.x, acc[4]);
      acc[5] = fmaf(e, h1.y, acc[5]);
      acc[6] = fmaf(e, h1.z, acc[6]);
      acc[7] = fmaf(e, h1.w, acc[7]);
    }
  }

  // butterfly reduce z + acc over the 8 e8-groups
  #pragma unroll
  for (int off = 8; off < 64; off <<= 1){
    z += __shfl_xor(z, off, 64);
    #pragma unroll
    for (int j = 0; j < 8; ++j) acc[j] += __shfl_xor(acc[j], off, 64);
  }

  if (e8 == 0){
    float inv = 1.0f / (z + 1e-16f);
    const float4* bp = (const float4*)(bias + c8 * 8);
    float4 b0 = bp[0], b1 = bp[1];
    float4 o0, o1;
    o0.x = acc[0] * inv + b0.x;
    o0.y = acc[1] * inv + b0.y;
    o0.z = acc[2] * inv + b0.z;
    o0.w = acc[3] * inv + b0.w;
    o1.x = acc[4] * inv + b1.x;
    o1.y = acc[5] * inv + b1.y;
    o1.z = acc[6] * inv + b1.z;
    o1.w = acc[7] * inv + b1.w;
    float4* op = (float4*)(out + (size_t)node * 64 + c8 * 8);
    op[0] = o0;
    op[1] = o1;
  }
}

// ---------------------------------------------------------------- launch
extern "C" void kernel_launch(void* const* d_in, const int* in_sizes, int n_in,
                              void* d_out, int out_size, void* d_ws, size_t ws_size,
                              hipStream_t stream){
  const float* x0   = (const float*)d_in[0];
  const int*   eidx = (const int*)  d_in[1];   // [2, E]
  const float* Ws   = (const float*)d_in[2];   // [L, 64, 64]
  const float* asrc = (const float*)d_in[3];   // [L, 8, 8]
  const float* adst = (const float*)d_in[4];   // [L, 8, 8]
  const float* bias = (const float*)d_in[5];   // [L, 64]

  const int N = in_sizes[0] / 64;
  const int E = in_sizes[1] / 2;
  const int L = in_sizes[2] / (64 * 64);

  char* ws = (char*)d_ws;
  size_t off = 0;
  auto alloc = [&](size_t bytes) -> void* {
    void* p = ws + off;
    off = (off + bytes + 255) & ~(size_t)255;
    return p;
  };
  float* hbuf    = (float*)alloc((size_t)N * 64 * sizeof(float));
  float* bufA    = (float*)alloc((size_t)N * 64 * sizeof(float));
  float* bufB    = (float*)alloc((size_t)N * 64 * sizeof(float));
  float* ssrc    = (float*)alloc((size_t)N * 8 * sizeof(float));
  float* sdstb   = (float*)alloc((size_t)N * 8 * sizeof(float));
  int*   counts  = (int*)alloc((size_t)N * sizeof(int));
  int*   offsets = (int*)alloc((size_t)(N + 1) * sizeof(int));
  int*   cursor  = (int*)alloc((size_t)N * sizeof(int));
  int*   ssorted = (int*)alloc((size_t)E * sizeof(int));

  const int* esrc = eidx;
  const int* edst = eidx + E;

  // CSR by destination — built once, reused by all layers
  zero_i32<<<ceil_div(N, 256), 256, 0, stream>>>(counts, N);
  hist_kernel<<<ceil_div(E, 256), 256, 0, stream>>>(edst, counts, E);
  scan_kernel<<<1, 1024, 0, stream>>>(counts, offsets, cursor, N);
  scatter_kernel<<<ceil_div(E, 256), 256, 0, stream>>>(esrc, edst, cursor, ssorted, E);

  float* bufs[2] = {bufA, bufB};
  for (int l = 0; l < L; ++l){
    const float* xin  = (l == 0)     ? x0 : bufs[(l - 1) & 1];
    float*       xout = (l == L - 1) ? (float*)d_out : bufs[l & 1];
    gemm_fused<<<ceil_div(N, 32), 256, 0, stream>>>(
        xin, Ws + (size_t)l * 64 * 64, asrc + l * 64, adst + l * 64,
        hbuf, ssrc, sdstb, N);
    aggregate<<<ceil_div(N * 64, 256), 256, 0, stream>>>(
        hbuf, ssrc, sdstb, offsets, ssorted, bias + l * 64, xout, N);
  }
}

// Round 6
// 437.714 us; speedup vs baseline: 2.5095x; 1.0053x over previous
//
#include <hip/hip_runtime.h>
#include <stdint.h>

#define NEG_SLOPE 0.2f

static inline int ceil_div(int a, int b){ return (a + b - 1) / b; }

// ---------------------------------------------------------------- CSR build
__global__ __launch_bounds__(256) void zero_i32(int* __restrict__ p, int n){
  int i = blockIdx.x * 256 + threadIdx.x;
  if (i < n) p[i] = 0;
}

__global__ __launch_bounds__(256) void hist_kernel(const int* __restrict__ dst,
                                                   int* __restrict__ counts, int E){
  int i = blockIdx.x * 256 + threadIdx.x;
  if (i < E) atomicAdd(counts + dst[i], 1);
}

// single-block exclusive scan of counts[n] -> offsets[n+1], cursor[n]
__global__ __launch_bounds__(1024) void scan_kernel(const int* __restrict__ counts,
                                                    int* __restrict__ offsets,
                                                    int* __restrict__ cursor, int n){
  __shared__ int lds[1024];
  const int tid = threadIdx.x;
  const int chunk = (n + 1023) >> 10;
  const int beg = tid * chunk;
  const int end = min(beg + chunk, n);
  int s = 0;
  for (int i = beg; i < end; ++i) s += counts[i];
  lds[tid] = s;
  __syncthreads();
  for (int off = 1; off < 1024; off <<= 1){
    int t = 0;
    if (tid >= off) t = lds[tid - off];
    __syncthreads();
    if (tid >= off) lds[tid] += t;
    __syncthreads();
  }
  int run = lds[tid] - s;
  for (int i = beg; i < end; ++i){
    offsets[i] = run;
    cursor[i]  = run;
    run += counts[i];
  }
  if (tid == 1023) offsets[n] = lds[1023];
}

__global__ __launch_bounds__(256) void scatter_kernel(const int* __restrict__ srcv,
                                                      const int* __restrict__ dstv,
                                                      int* __restrict__ cursor,
                                                      int* __restrict__ sorted_src, int E){
  int i = blockIdx.x * 256 + threadIdx.x;
  if (i < E){
    int d = dstv[i];
    int pos = atomicAdd(cursor + d, 1);
    if (pos >= 0 && pos < E) sorted_src[pos] = srcv[i];  // clamp: rocprof replay safety
  }
}

// ------------------------------------------------- per-layer: h = x@W (+ fused a·h)
// 16 rows/block (grid 2x vs 32-row version -> ~5 blocks/CU), 2-way k-split ILP.
// h is stored PERMUTED: word = half*32 + c8*4 + k  holds channel c8*8 + half*4 + k,
// so aggregate's 8-lane gathers read contiguous 128B blocks (4 full lines/edge).
// perm_in: input rows are in permuted word order (intermediate layers) -> remap W rows.
__global__ __launch_bounds__(256) void gemm_fused(const float* __restrict__ x,
                                                  const float* __restrict__ W,
                                                  const float* __restrict__ a_src,
                                                  const float* __restrict__ a_dst,
                                                  float* __restrict__ h,
                                                  float* __restrict__ s_src,
                                                  float* __restrict__ s_dst,
                                                  int N, int perm_in){
  __shared__ float xlds[16 * 64];
  const int tid  = threadIdx.x;
  const int lane = tid & 63;
  const int wave = tid >> 6;
  const int row0 = blockIdx.x * 16;

  // W column `lane`, rows in the input-word order (identity or permuted)
  float wreg[64];
  #pragma unroll
  for (int s = 0; s < 64; ++s){
    int c = perm_in ? (((s >> 2) & 7) * 8 + (s >> 5) * 4 + (s & 3)) : s;
    wreg[s] = W[c * 64 + lane];
  }

  {
    const float4* xg = (const float4*)x;
    int r = row0 + (tid >> 4);
    float4 v = {0.f, 0.f, 0.f, 0.f};
    if (r < N) v = xg[(size_t)r * 16 + (tid & 15)];
    ((float4*)xlds)[tid] = v;
  }
  __syncthreads();

  const float asv = a_src[lane];
  const float adv = a_dst[lane];
  // permuted store word for output channel `lane`
  const int hword = ((lane >> 3) << 2) | (lane & 3) | ((lane & 4) << 3);

  for (int r = wave; r < 16; r += 4){
    int row = row0 + r;
    if (row >= N) break;               // uniform within wave
    const float4* xr = (const float4*)(xlds + r * 64);
    float a0 = 0.0f, a1 = 0.0f;        // 2 independent FMA chains
    #pragma unroll
    for (int kk = 0; kk < 8; ++kk){
      float4 xv = xr[kk];
      a0 = fmaf(xv.x, wreg[4*kk+0], a0);
      a0 = fmaf(xv.y, wreg[4*kk+1], a0);
      a0 = fmaf(xv.z, wreg[4*kk+2], a0);
      a0 = fmaf(xv.w, wreg[4*kk+3], a0);
    }
    #pragma unroll
    for (int kk = 8; kk < 16; ++kk){
      float4 xv = xr[kk];
      a1 = fmaf(xv.x, wreg[4*kk+0], a1);
      a1 = fmaf(xv.y, wreg[4*kk+1], a1);
      a1 = fmaf(xv.z, wreg[4*kk+2], a1);
      a1 = fmaf(xv.w, wreg[4*kk+3], a1);
    }
    float acc = a0 + a1;
    h[(size_t)row * 64 + hword] = acc;
    float ps = acc * asv;
    float pd = acc * adv;
    #pragma unroll
    for (int off = 1; off < 8; off <<= 1){
      ps += __shfl_xor(ps, off, 64);
      pd += __shfl_xor(pd, off, 64);
    }
    if ((lane & 7) == 0){
      s_src[row * 8 + (lane >> 3)] = ps;
      s_dst[row * 8 + (lane >> 3)] = pd;
    }
  }
}

// ------------------------------------- per-layer: segment softmax + aggregation
// one wave per node; lane = e8*8 + c8 (c8 = head, e8 = edge slot).
// h is permuted: lane c8 reads float4s at words s*64+c8*4 and s*64+32+c8*4 ->
// the 8 lanes of an edge cover two contiguous 128B blocks (4 full lines, no waste).
// h-gathers are issued BEFORE the max butterfly so their latency overlaps it.
// perm_out: store permuted (intermediate) or natural (last layer).
__global__ __launch_bounds__(256) void aggregate(const float* __restrict__ h,
                                                 const float* __restrict__ s_src,
                                                 const float* __restrict__ s_dst,
                                                 const int* __restrict__ offsets,
                                                 const int* __restrict__ sorted_src,
                                                 const float* __restrict__ bias,
                                                 float* __restrict__ out,
                                                 int N, int E, int perm_out){
  const int node = (blockIdx.x * 256 + threadIdx.x) >> 6;
  if (node >= N) return;
  const int lane = threadIdx.x & 63;
  const int c8 = lane & 7;            // head / channel group
  const int e8 = lane >> 3;           // edge slot
  // clamp against rocprof dispatch-replay with poisoned workspace
  int beg = offsets[node];
  int end = offsets[node + 1];
  beg = max(0, min(beg, E));
  end = max(0, min(end, E));
  const int nv = end - beg + 1;       // +1 self-loop (slot 0); may be <=0 if poisoned
  const float sdst = s_dst[node * 8 + c8];

  float m = -3.0e38f;
  float z = 0.0f;
  float acc[8];
  #pragma unroll
  for (int j = 0; j < 8; ++j) acc[j] = 0.0f;

  if (nv <= 64){
    const int cnt = (e8 < nv) ? ((nv - e8 + 7) >> 3) : 0;
    // phase 1: edge indices (independent)
    int sidx[8];
    #pragma unroll
    for (int j = 0; j < 8; ++j){
      int v = e8 + 8 * j;
      if (j < cnt) sidx[j] = (v == 0) ? node : sorted_src[beg + v - 1];
    }
    // phase 2: score gathers
    float sc[8];
    #pragma unroll
    for (int j = 0; j < 8; ++j){
      if (j < cnt){
        float s = s_src[sidx[j] * 8 + c8] + sdst;
        sc[j] = (s > 0.0f) ? s : NEG_SLOPE * s;
      }
    }
    // phase 2b: issue h gathers NOW (independent of the max) -> overlap butterfly
    float4 h0r[8], h1r[8];
    #pragma unroll
    for (int j = 0; j < 8; ++j){
      if (j < cnt){
        const float4* hp = (const float4*)(h + (size_t)sidx[j] * 64 + c8 * 4);
        h0r[j] = hp[0];
        h1r[j] = hp[8];               // +32 words = +128B
      }
    }
    // per-head max + butterfly
    #pragma unroll
    for (int j = 0; j < 8; ++j)
      if (j < cnt) m = fmaxf(m, sc[j]);
    m = fmaxf(m, __shfl_xor(m, 8, 64));
    m = fmaxf(m, __shfl_xor(m, 16, 64));
    m = fmaxf(m, __shfl_xor(m, 32, 64));
    // phase 3: pure VALU consume
    #pragma unroll
    for (int j = 0; j < 8; ++j){
      if (j < cnt){
        float e = __expf(sc[j] - m);
        z += e;
        acc[0] = fmaf(e, h0r[j].x, acc[0]);
        acc[1] = fmaf(e, h0r[j].y, acc[1]);
        acc[2] = fmaf(e, h0r[j].z, acc[2]);
        acc[3] = fmaf(e, h0r[j].w, acc[3]);
        acc[4] = fmaf(e, h1r[j].x, acc[4]);
        acc[5] = fmaf(e, h1r[j].y, acc[5]);
        acc[6] = fmaf(e, h1r[j].z, acc[6]);
        acc[7] = fmaf(e, h1r[j].w, acc[7]);
      }
    }
  } else {
    // slow streaming path (rare: nv > 64)
    for (int v = e8; v < nv; v += 8){
      int s = (v == 0) ? node : sorted_src[beg + v - 1];
      float scv = s_src[s * 8 + c8] + sdst;
      scv = (scv > 0.0f) ? scv : NEG_SLOPE * scv;
      m = fmaxf(m, scv);
    }
    m = fmaxf(m, __shfl_xor(m, 8, 64));
    m = fmaxf(m, __shfl_xor(m, 16, 64));
    m = fmaxf(m, __shfl_xor(m, 32, 64));
    for (int v = e8; v < nv; v += 8){
      int s = (v == 0) ? node : sorted_src[beg + v - 1];
      float scv = s_src[s * 8 + c8] + sdst;
      scv = (scv > 0.0f) ? scv : NEG_SLOPE * scv;
      float e = __expf(scv - m);
      z += e;
      const float4* hp = (const float4*)(h + (size_t)s * 64 + c8 * 4);
      float4 h0 = hp[0];
      float4 h1 = hp[8];
      acc[0] = fmaf(e, h0.x, acc[0]);
      acc[1] = fmaf(e, h0.y, acc[1]);
      acc[2] = fmaf(e, h0.z, acc[2]);
      acc[3] = fmaf(e, h0.w, acc[3]);
      acc[4] = fmaf(e, h1.x, acc[4]);
      acc[5] = fmaf(e, h1.y, acc[5]);
      acc[6] = fmaf(e, h1.z, acc[6]);
      acc[7] = fmaf(e, h1.w, acc[7]);
    }
  }

  // butterfly reduce z + acc over the 8 e8-groups
  #pragma unroll
  for (int off = 8; off < 64; off <<= 1){
    z += __shfl_xor(z, off, 64);
    #pragma unroll
    for (int j = 0; j < 8; ++j) acc[j] += __shfl_xor(acc[j], off, 64);
  }

  if (e8 == 0){
    float inv = 1.0f / (z + 1e-16f);
    const float4* bp = (const float4*)(bias + c8 * 8);   // channels c8*8..+7
    float4 b0 = bp[0], b1 = bp[1];
    float4 o0, o1;
    o0.x = acc[0] * inv + b0.x;
    o0.y = acc[1] * inv + b0.y;
    o0.z = acc[2] * inv + b0.z;
    o0.w = acc[3] * inv + b0.w;
    o1.x = acc[4] * inv + b1.x;
    o1.y = acc[5] * inv + b1.y;
    o1.z = acc[6] * inv + b1.z;
    o1.w = acc[7] * inv + b1.w;
    if (perm_out){
      // permuted: words c8*4 (half0) and 32+c8*4 (half1)
      float4* op = (float4*)(out + (size_t)node * 64);
      op[c8]     = o0;
      op[8 + c8] = o1;
    } else {
      // natural: channels c8*8..+7 contiguous
      float4* op = (float4*)(out + (size_t)node * 64 + c8 * 8);
      op[0] = o0;
      op[1] = o1;
    }
  }
}

// ---------------------------------------------------------------- launch
extern "C" void kernel_launch(void* const* d_in, const int* in_sizes, int n_in,
                              void* d_out, int out_size, void* d_ws, size_t ws_size,
                              hipStream_t stream){
  const float* x0   = (const float*)d_in[0];
  const int*   eidx = (const int*)  d_in[1];   // [2, E]
  const float* Ws   = (const float*)d_in[2];   // [L, 64, 64]
  const float* asrc = (const float*)d_in[3];   // [L, 8, 8]
  const float* adst = (const float*)d_in[4];   // [L, 8, 8]
  const float* bias = (const float*)d_in[5];   // [L, 64]

  const int N = in_sizes[0] / 64;
  const int E = in_sizes[1] / 2;
  const int L = in_sizes[2] / (64 * 64);

  char* ws = (char*)d_ws;
  size_t off = 0;
  auto alloc = [&](size_t bytes) -> void* {
    void* p = ws + off;
    off = (off + bytes + 255) & ~(size_t)255;
    return p;
  };
  float* hbuf    = (float*)alloc((size_t)N * 64 * sizeof(float));
  float* bufA    = (float*)alloc((size_t)N * 64 * sizeof(float));
  float* bufB    = (float*)alloc((size_t)N * 64 * sizeof(float));
  float* ssrc    = (float*)alloc((size_t)N * 8 * sizeof(float));
  float* sdstb   = (float*)alloc((size_t)N * 8 * sizeof(float));
  int*   counts  = (int*)alloc((size_t)N * sizeof(int));
  int*   offsets = (int*)alloc((size_t)(N + 1) * sizeof(int));
  int*   cursor  = (int*)alloc((size_t)N * sizeof(int));
  int*   ssorted = (int*)alloc((size_t)E * sizeof(int));

  const int* esrc = eidx;
  const int* edst = eidx + E;

  // CSR by destination — built once, reused by all layers
  zero_i32<<<ceil_div(N, 256), 256, 0, stream>>>(counts, N);
  hist_kernel<<<ceil_div(E, 256), 256, 0, stream>>>(edst, counts, E);
  scan_kernel<<<1, 1024, 0, stream>>>(counts, offsets, cursor, N);
  scatter_kernel<<<ceil_div(E, 256), 256, 0, stream>>>(esrc, edst, cursor, ssorted, E);

  float* bufs[2] = {bufA, bufB};
  for (int l = 0; l < L; ++l){
    const float* xin  = (l == 0)     ? x0 : bufs[(l - 1) & 1];
    float*       xout = (l == L - 1) ? (float*)d_out : bufs[l & 1];
    gemm_fused<<<ceil_div(N, 16), 256, 0, stream>>>(
        xin, Ws + (size_t)l * 64 * 64, asrc + l * 64, adst + l * 64,
        hbuf, ssrc, sdstb, N, (l > 0) ? 1 : 0);
    aggregate<<<ceil_div(N * 64, 256), 256, 0, stream>>>(
        hbuf, ssrc, sdstb, offsets, ssorted, bias + l * 64, xout,
        N, E, (l < L - 1) ? 1 : 0);
  }
}